// Round 7
// baseline (437.037 us; speedup 1.0000x reference)
//
#include <hip/hip_runtime.h>
#include <math.h>

#define D 128

__device__ __forceinline__ float sigmoidf_(float x) { return 1.0f / (1.0f + expf(-x)); }

// ---- degree histogram over dst ----
__global__ void k_deg(const int* __restrict__ dst, int* __restrict__ cnt, int E) {
    int i = blockIdx.x * blockDim.x + threadIdx.x;
    if (i < E) atomicAdd(&cnt[dst[i]], 1);
}

// ---- 2-level scan (+ dinv + fillc-zero fused into pass 1, gstart fused into pass 2) ----
__global__ __launch_bounds__(256) void k_scan1(const int* __restrict__ cnt, int* __restrict__ row_ptr,
                                               int* __restrict__ bsum, float* __restrict__ dinv,
                                               int* __restrict__ fillc, int N) {
    __shared__ int sh[256];
    int t = threadIdx.x;
    int i = blockIdx.x * 256 + t;
    int v = (i < N) ? cnt[i] : 0;
    if (i < N) {
        dinv[i] = rsqrtf((float)v + 1.0f);
        fillc[i] = 0;
    }
    sh[t] = v;
    __syncthreads();
    for (int off = 1; off < 256; off <<= 1) {
        int u = (t >= off) ? sh[t - off] : 0;
        __syncthreads();
        sh[t] += u;
        __syncthreads();
    }
    if (i < N) row_ptr[i] = sh[t] - v;
    if (t == 255) bsum[blockIdx.x] = sh[255];
}

__global__ __launch_bounds__(256) void k_scan2(int* __restrict__ bsum, int nb,
                                               const int* __restrict__ batch, int* __restrict__ gstart,
                                               int N, int G) {
    __shared__ int sh[256];
    int t = threadIdx.x;
    int v = (t < nb) ? bsum[t] : 0;
    sh[t] = v;
    __syncthreads();
    for (int off = 1; off < 256; off <<= 1) {
        int u = (t >= off) ? sh[t - off] : 0;
        __syncthreads();
        sh[t] += u;
        __syncthreads();
    }
    if (t < nb) bsum[t] = sh[t] - v;
    for (int g = t; g <= G; g += 256) {
        int lo = 0, hi = N;
        while (lo < hi) {
            int mid = (lo + hi) >> 1;
            if (batch[mid] < g) lo = mid + 1; else hi = mid;
        }
        gstart[g] = lo;
    }
}

__global__ __launch_bounds__(256) void k_scan3(int* __restrict__ row_ptr, const int* __restrict__ bsum,
                                               int N, int E) {
    int i = blockIdx.x * 256 + threadIdx.x;
    if (i < N) row_ptr[i] += bsum[blockIdx.x];
    if (i == 0) row_ptr[N] = E;
}

// ---- counting-sort fill: ONLY the source-index scatter (2 random line-ops/edge) ----
__global__ void k_fill(const int* __restrict__ src, const int* __restrict__ dst,
                       const int* __restrict__ row_ptr, int* __restrict__ fillc,
                       int* __restrict__ s_sorted, int E) {
    int i = blockIdx.x * blockDim.x + threadIdx.x;
    if (i >= E) return;
    int s = src[i], d = dst[i];
    int pos = row_ptr[d] + atomicAdd(&fillc[d], 1);
    s_sorted[pos] = s;
}

// ---- Wcomb[k][j] = Wih[j][k] + (k<128 ? Whh[j][k] : 0) ; [256][512] ----
__global__ __launch_bounds__(256) void k_prepw(const float* __restrict__ Wih, const float* __restrict__ Whh,
                                               float* __restrict__ Wcomb) {
    __shared__ float ta[32][33], tb[32][33];
    int t = threadIdx.x;
    int tx = t & 31, ty = t >> 5;
    int bk = blockIdx.x & 7, bj = blockIdx.x >> 3;
    int k0 = bk * 32, j0 = bj * 32;
    bool hh = (k0 < 128);
#pragma unroll
    for (int i = 0; i < 32; i += 8) ta[ty + i][tx] = Wih[(size_t)(j0 + ty + i) * 256 + k0 + tx];
    if (hh) {
#pragma unroll
        for (int i = 0; i < 32; i += 8) tb[ty + i][tx] = Whh[(size_t)(j0 + ty + i) * 128 + k0 + tx];
    }
    __syncthreads();
#pragma unroll
    for (int i = 0; i < 32; i += 8) {
        float v = ta[tx][ty + i];
        if (hh) v += tb[tx][ty + i];
        Wcomb[(size_t)(k0 + ty + i) * 512 + j0 + tx] = v;
    }
}

// ---- FP32 GEMM: Y[M,128] = X[M,128] @ W[128,128], 128x128 tile, 8x8 acc ----
// column split tc*4 / 64+tc*4 keeps LDS reads at free 2-way bank aliasing
__global__ __launch_bounds__(256) void k_gemm(const float* __restrict__ X, const float* __restrict__ W,
                                              float* __restrict__ Y, int M) {
    __shared__ float Xs[32][136];   // [k][row], padded
    __shared__ float Ws[32][128];
    int block_row = blockIdx.x * 128;
    int tid = threadIdx.x;
    int trr = tid >> 4;   // 0..15 -> rows trr*8..+7
    int tc = tid & 15;    // cols tc*4..+3 and 64+tc*4..+3
    float acc[8][8] = {};
    for (int k0 = 0; k0 < 128; k0 += 32) {
        for (int i = tid; i < 1024; i += 256) {
            int r = i >> 3, kk = (i & 7) << 2;
            int row = block_row + r;
            float4 v = make_float4(0.f, 0.f, 0.f, 0.f);
            if (row < M) v = *(const float4*)&X[(size_t)row * D + k0 + kk];
            Xs[kk + 0][r] = v.x; Xs[kk + 1][r] = v.y; Xs[kk + 2][r] = v.z; Xs[kk + 3][r] = v.w;
        }
        for (int i = tid; i < 1024; i += 256) {
            int r = i >> 5, cc = (i & 31) << 2;
            *(float4*)&Ws[r][cc] = *(const float4*)&W[(size_t)(k0 + r) * D + cc];
        }
        __syncthreads();
#pragma unroll
        for (int k = 0; k < 32; ++k) {
            float4 x0 = *(const float4*)&Xs[k][trr * 8];
            float4 x1 = *(const float4*)&Xs[k][trr * 8 + 4];
            float4 w0 = *(const float4*)&Ws[k][tc * 4];
            float4 w1 = *(const float4*)&Ws[k][64 + tc * 4];
            float xr[8] = {x0.x, x0.y, x0.z, x0.w, x1.x, x1.y, x1.z, x1.w};
            float wc[8] = {w0.x, w0.y, w0.z, w0.w, w1.x, w1.y, w1.z, w1.w};
#pragma unroll
            for (int r = 0; r < 8; ++r)
#pragma unroll
                for (int c = 0; c < 8; ++c)
                    acc[r][c] += xr[r] * wc[c];
        }
        __syncthreads();
    }
#pragma unroll
    for (int r = 0; r < 8; ++r) {
        int row = block_row + trr * 8 + r;
        if (row < M) {
            *(float4*)&Y[(size_t)row * D + tc * 4] = make_float4(acc[r][0], acc[r][1], acc[r][2], acc[r][3]);
            *(float4*)&Y[(size_t)row * D + 64 + tc * 4] = make_float4(acc[r][4], acc[r][5], acc[r][6], acc[r][7]);
        }
    }
}

// ---- CSR gather aggregation, wave-per-node, 8 rows in flight ----
// norm factored: out[n] = dinv[n] * sum_e dinv[s]*xw[s] + xw[n]*dinv[n]^2 + b
template <bool RELU>
__global__ __launch_bounds__(256) void k_agg(const float* __restrict__ xw, const int* __restrict__ s_sorted,
                                             const int* __restrict__ row_ptr, const float* __restrict__ dinv,
                                             const float* __restrict__ bias, float* __restrict__ out, int N) {
    int n = blockIdx.x * 4 + (threadIdx.x >> 6);
    if (n >= N) return;
    int l = threadIdx.x & 63;
    int beg = row_ptr[n], end = row_ptr[n + 1];
    float2 a[8];
#pragma unroll
    for (int k = 0; k < 8; ++k) a[k] = make_float2(0.f, 0.f);
    for (int e = beg; e < end; e += 8) {
#pragma unroll
        for (int k = 0; k < 8; ++k) {
            int ee = min(e + k, end - 1);
            int s = s_sorted[ee];
            float ds = dinv[s];                 // L2-hot broadcast (200KB array)
            ds = (e + k < end) ? ds : 0.f;
            float2 xv = *(const float2*)&xw[(size_t)s * D + 2 * l];
            a[k].x += xv.x * ds;
            a[k].y += xv.y * ds;
        }
    }
    float din = dinv[n];
    float dw = din * din;
    float2 xs = *(const float2*)&xw[(size_t)n * D + 2 * l];
    float2 bv = *(const float2*)&bias[2 * l];
    float rx = (((a[0].x + a[1].x) + (a[2].x + a[3].x)) + ((a[4].x + a[5].x) + (a[6].x + a[7].x))) * din
               + xs.x * dw + bv.x;
    float ry = (((a[0].y + a[1].y) + (a[2].y + a[3].y)) + ((a[4].y + a[5].y) + (a[6].y + a[7].y))) * din
               + xs.y * dw + bv.y;
    if (RELU) { rx = fmaxf(rx, 0.f); ry = fmaxf(ry, 0.f); }
    *(float2*)&out[(size_t)n * D + 2 * l] = make_float2(rx, ry);
}

// ---- batched LSTM gates GEMM: gates[256][512] = q_star[256][256] @ Wcomb[256][512] ----
__global__ __launch_bounds__(256) void k_lstm_gemm(const float* __restrict__ q_star,
                                                   const float* __restrict__ Wcomb,
                                                   float* __restrict__ gates) {
    __shared__ float Xs[32][68];
    __shared__ float Ws[32][64];
    int tid = threadIdx.x;
    int bm = blockIdx.x & 3, bn = blockIdx.x >> 2;
    int m0 = bm * 64, n0 = bn * 64;
    int trr = tid >> 4;
    int tc = tid & 15;
    float acc[4][4] = {};
    for (int k0 = 0; k0 < 256; k0 += 32) {
        for (int i = tid; i < 512; i += 256) {
            int r = i >> 3, kk = (i & 7) << 2;
            float4 v = *(const float4*)&q_star[(size_t)(m0 + r) * 256 + k0 + kk];
            Xs[kk + 0][r] = v.x; Xs[kk + 1][r] = v.y; Xs[kk + 2][r] = v.z; Xs[kk + 3][r] = v.w;
        }
        for (int i = tid; i < 512; i += 256) {
            int r = i >> 4, c = (i & 15) << 2;
            *(float4*)&Ws[r][c] = *(const float4*)&Wcomb[(size_t)(k0 + r) * 512 + n0 + c];
        }
        __syncthreads();
#pragma unroll
        for (int k = 0; k < 32; ++k) {
            float4 xv = *(const float4*)&Xs[k][trr * 4];
            float4 wv = *(const float4*)&Ws[k][tc * 4];
            float xr[4] = {xv.x, xv.y, xv.z, xv.w};
            float wc[4] = {wv.x, wv.y, wv.z, wv.w};
#pragma unroll
            for (int r = 0; r < 4; ++r)
#pragma unroll
                for (int c = 0; c < 4; ++c)
                    acc[r][c] += xr[r] * wc[c];
        }
        __syncthreads();
    }
#pragma unroll
    for (int r = 0; r < 4; ++r)
        *(float4*)&gates[(size_t)(m0 + trr * 4 + r) * 512 + n0 + tc * 4] =
            make_float4(acc[r][0], acc[r][1], acc[r][2], acc[r][3]);
}

// ---- per-graph: LSTM nonlinearity prologue + SINGLE-PASS online-softmax attention ----
template <bool FIRST>
__global__ __launch_bounds__(512) void k_attn2(const float* __restrict__ h2, const int* __restrict__ gstart,
                                               const float* __restrict__ gates, const float* __restrict__ bih,
                                               const float* __restrict__ bhh, float* __restrict__ c_all,
                                               float* __restrict__ q_star) {
    int g = blockIdx.x;
    int t = threadIdx.x;
    int wid = t >> 6, l = t & 63;
    int s = gstart[g], epos = gstart[g + 1];
    __shared__ float hs[D];
    __shared__ float wmax[8], wsum[8];
    __shared__ float2 racc2[512];
    if (t < D) {
        float ig = bih[t] + bhh[t];
        float fg = bih[t + D] + bhh[t + D];
        float gg = bih[t + 2 * D] + bhh[t + 2 * D];
        float og = bih[t + 3 * D] + bhh[t + 3 * D];
        if (!FIRST) {
            const float* gr = &gates[(size_t)g * 512];
            ig += gr[t]; fg += gr[t + D]; gg += gr[t + 2 * D]; og += gr[t + 3 * D];
        }
        float cprev = FIRST ? 0.f : c_all[g * D + t];
        float cc = sigmoidf_(fg) * cprev + sigmoidf_(ig) * tanhf(gg);
        float hh = sigmoidf_(og) * tanhf(cc);
        c_all[g * D + t] = cc;
        hs[t] = hh;
        q_star[(size_t)g * 2 * D + t] = hh;
    }
    __syncthreads();
    float2 qv = *(const float2*)&hs[2 * l];
    float m = -1e30f;
    float ssum = 0.f;
    float2 a = {0.f, 0.f};
    for (int i = s + wid * 4; i < epos; i += 32) {
        int i0 = i, i1 = min(i + 1, epos - 1), i2 = min(i + 2, epos - 1), i3 = min(i + 3, epos - 1);
        bool v1 = (i + 1 < epos), v2 = (i + 2 < epos), v3 = (i + 3 < epos);
        float2 x0 = *(const float2*)&h2[(size_t)i0 * D + 2 * l];
        float2 x1 = *(const float2*)&h2[(size_t)i1 * D + 2 * l];
        float2 x2 = *(const float2*)&h2[(size_t)i2 * D + 2 * l];
        float2 x3 = *(const float2*)&h2[(size_t)i3 * D + 2 * l];
        float d0 = x0.x * qv.x + x0.y * qv.y;
        float d1 = x1.x * qv.x + x1.y * qv.y;
        float d2 = x2.x * qv.x + x2.y * qv.y;
        float d3 = x3.x * qv.x + x3.y * qv.y;
#pragma unroll
        for (int off = 32; off; off >>= 1) {
            d0 += __shfl_xor(d0, off);
            d1 += __shfl_xor(d1, off);
            d2 += __shfl_xor(d2, off);
            d3 += __shfl_xor(d3, off);
        }
        {
            if (d0 > m) { float sc = expf(m - d0); a.x *= sc; a.y *= sc; ssum *= sc; m = d0; }
            float p = expf(d0 - m);
            ssum += p; a.x += p * x0.x; a.y += p * x0.y;
        }
        if (v1) {
            if (d1 > m) { float sc = expf(m - d1); a.x *= sc; a.y *= sc; ssum *= sc; m = d1; }
            float p = expf(d1 - m);
            ssum += p; a.x += p * x1.x; a.y += p * x1.y;
        }
        if (v2) {
            if (d2 > m) { float sc = expf(m - d2); a.x *= sc; a.y *= sc; ssum *= sc; m = d2; }
            float p = expf(d2 - m);
            ssum += p; a.x += p * x2.x; a.y += p * x2.y;
        }
        if (v3) {
            if (d3 > m) { float sc = expf(m - d3); a.x *= sc; a.y *= sc; ssum *= sc; m = d3; }
            float p = expf(d3 - m);
            ssum += p; a.x += p * x3.x; a.y += p * x3.y;
        }
    }
    if (l == 0) wmax[wid] = m;
    __syncthreads();
    float M = wmax[0];
#pragma unroll
    for (int w = 1; w < 8; ++w) M = fmaxf(M, wmax[w]);
    float fac = expf(m - M);
    a.x *= fac; a.y *= fac;
    ssum *= fac;
    if (l == 0) wsum[wid] = ssum;
    racc2[t] = a;
    __syncthreads();
    if (t < 64) {
        float S = 0.f;
#pragma unroll
        for (int w = 0; w < 8; ++w) S += wsum[w];
        float2 r = make_float2(0.f, 0.f);
#pragma unroll
        for (int w = 0; w < 8; ++w) { r.x += racc2[t + 64 * w].x; r.y += racc2[t + 64 * w].y; }
        float inv = 1.0f / (S + 1e-16f);
        q_star[(size_t)g * 2 * D + D + 2 * t] = r.x * inv;
        q_star[(size_t)g * 2 * D + D + 2 * t + 1] = r.y * inv;
    }
}

extern "C" void kernel_launch(void* const* d_in, const int* in_sizes, int n_in,
                              void* d_out, int out_size, void* d_ws, size_t ws_size,
                              hipStream_t stream) {
    const float* x = (const float*)d_in[0];
    const int* ei = (const int*)d_in[1];
    const int* batch = (const int*)d_in[2];
    const float* W1 = (const float*)d_in[3];
    const float* b1 = (const float*)d_in[4];
    const float* W2 = (const float*)d_in[5];
    const float* b2 = (const float*)d_in[6];
    const float* Wih = (const float*)d_in[7];
    const float* Whh = (const float*)d_in[8];
    const float* bih = (const float*)d_in[9];
    const float* bhh = (const float*)d_in[10];

    int N = in_sizes[2];          // 50000
    int E = in_sizes[1] / 2;      // 625000
    int G = out_size / (2 * D);   // 256
    const int* src = ei;
    const int* dst = ei + E;
    float* xbuf = (float*)d_in[0];  // reuse x's buffer for h1/h2 (inputs restored before every call)
    float* q_star = (float*)d_out;

    float* wsf = (float*)d_ws;
    int* wsi = (int*)d_ws;
    size_t off = 0;
    float* dinv = wsf + off;    off += N;
    int* degcnt = wsi + off;    off += N;
    int* row_ptr = wsi + off;   off += N + 1;
    int* bsum = wsi + off;      off += 256;
    off = (off + 3) & ~(size_t)3;
    int* fillc = wsi + off;     off += N;
    int* s_sorted = wsi + off;  off += E;
    off = (off + 3) & ~(size_t)3;
    float* bufA = wsf + off;    off += (size_t)N * D;
    int* gstart = wsi + off;    off += G + 1;
    off = (off + 3) & ~(size_t)3;
    float* Wcomb = wsf + off;   off += 256 * 512;
    float* gates = wsf + off;   off += (size_t)G * 512;
    float* c_all = wsf + off;   off += (size_t)G * D;

    hipMemsetAsync(degcnt, 0, N * sizeof(int), stream);

    int eb = (E + 255) / 256;
    int nb = (N + 255) / 256;
    k_deg<<<eb, 256, 0, stream>>>(dst, degcnt, E);
    k_scan1<<<nb, 256, 0, stream>>>(degcnt, row_ptr, bsum, dinv, fillc, N);
    k_scan2<<<1, 256, 0, stream>>>(bsum, nb, batch, gstart, N, G);
    k_scan3<<<nb, 256, 0, stream>>>(row_ptr, bsum, N, E);
    k_fill<<<eb, 256, 0, stream>>>(src, dst, row_ptr, fillc, s_sorted, E);
    k_prepw<<<128, 256, 0, stream>>>(Wih, Whh, Wcomb);

    int gb = (N + 127) / 128;
    k_gemm<<<gb, 256, 0, stream>>>(x, W1, bufA, N);
    k_agg<true><<<(N + 3) / 4, 256, 0, stream>>>(bufA, s_sorted, row_ptr, dinv, b1, xbuf, N);
    k_gemm<<<gb, 256, 0, stream>>>(xbuf, W2, bufA, N);
    k_agg<false><<<(N + 3) / 4, 256, 0, stream>>>(bufA, s_sorted, row_ptr, dinv, b2, xbuf, N);

    // step 0: q_star = 0 -> gates are pure biases; no GEMM needed
    k_attn2<true><<<G, 512, 0, stream>>>(xbuf, gstart, gates, bih, bhh, c_all, q_star);
    for (int step = 1; step < 3; ++step) {
        k_lstm_gemm<<<32, 256, 0, stream>>>(q_star, Wcomb, gates);
        k_attn2<false><<<G, 512, 0, stream>>>(xbuf, gstart, gates, bih, bhh, c_all, q_star);
    }
}

// Round 9
// 409.080 us; speedup vs baseline: 1.0683x; 1.0683x over previous
//
#include <hip/hip_runtime.h>
#include <math.h>

#define D 128

__device__ __forceinline__ float sigmoidf_(float x) { return 1.0f / (1.0f + expf(-x)); }

// ---- degree histogram over dst ----
__global__ void k_deg(const int* __restrict__ dst, int* __restrict__ cnt, int E) {
    int i = blockIdx.x * blockDim.x + threadIdx.x;
    if (i < E) atomicAdd(&cnt[dst[i]], 1);
}

// ---- 2-level scan (+ dinv + fillc-zero fused into pass 1, gstart fused into pass 2) ----
__global__ __launch_bounds__(256) void k_scan1(const int* __restrict__ cnt, int* __restrict__ row_ptr,
                                               int* __restrict__ bsum, float* __restrict__ dinv,
                                               int* __restrict__ fillc, int N) {
    __shared__ int sh[256];
    int t = threadIdx.x;
    int i = blockIdx.x * 256 + t;
    int v = (i < N) ? cnt[i] : 0;
    if (i < N) {
        dinv[i] = rsqrtf((float)v + 1.0f);
        fillc[i] = 0;
    }
    sh[t] = v;
    __syncthreads();
    for (int off = 1; off < 256; off <<= 1) {
        int u = (t >= off) ? sh[t - off] : 0;
        __syncthreads();
        sh[t] += u;
        __syncthreads();
    }
    if (i < N) row_ptr[i] = sh[t] - v;
    if (t == 255) bsum[blockIdx.x] = sh[255];
}

__global__ __launch_bounds__(256) void k_scan2(int* __restrict__ bsum, int nb,
                                               const int* __restrict__ batch, int* __restrict__ gstart,
                                               int N, int G) {
    __shared__ int sh[256];
    int t = threadIdx.x;
    int v = (t < nb) ? bsum[t] : 0;
    sh[t] = v;
    __syncthreads();
    for (int off = 1; off < 256; off <<= 1) {
        int u = (t >= off) ? sh[t - off] : 0;
        __syncthreads();
        sh[t] += u;
        __syncthreads();
    }
    if (t < nb) bsum[t] = sh[t] - v;
    for (int g = t; g <= G; g += 256) {
        int lo = 0, hi = N;
        while (lo < hi) {
            int mid = (lo + hi) >> 1;
            if (batch[mid] < g) lo = mid + 1; else hi = mid;
        }
        gstart[g] = lo;
    }
}

__global__ __launch_bounds__(256) void k_scan3(int* __restrict__ row_ptr, const int* __restrict__ bsum,
                                               int N, int E) {
    int i = blockIdx.x * 256 + threadIdx.x;
    if (i < N) row_ptr[i] += bsum[blockIdx.x];
    if (i == 0) row_ptr[N] = E;
}

// ---- counting-sort fill: ONLY the source-index scatter ----
__global__ void k_fill(const int* __restrict__ src, const int* __restrict__ dst,
                       const int* __restrict__ row_ptr, int* __restrict__ fillc,
                       int* __restrict__ s_sorted, int E) {
    int i = blockIdx.x * blockDim.x + threadIdx.x;
    if (i >= E) return;
    int s = src[i], d = dst[i];
    int pos = row_ptr[d] + atomicAdd(&fillc[d], 1);
    s_sorted[pos] = s;
}

// ---- Wcomb[k][j] = Wih[j][k] + (k<128 ? Whh[j][k] : 0) ; [256][512] ----
__global__ __launch_bounds__(256) void k_prepw(const float* __restrict__ Wih, const float* __restrict__ Whh,
                                               float* __restrict__ Wcomb) {
    __shared__ float ta[32][33], tb[32][33];
    int t = threadIdx.x;
    int tx = t & 31, ty = t >> 5;
    int bk = blockIdx.x & 7, bj = blockIdx.x >> 3;
    int k0 = bk * 32, j0 = bj * 32;
    bool hh = (k0 < 128);
#pragma unroll
    for (int i = 0; i < 32; i += 8) ta[ty + i][tx] = Wih[(size_t)(j0 + ty + i) * 256 + k0 + tx];
    if (hh) {
#pragma unroll
        for (int i = 0; i < 32; i += 8) tb[ty + i][tx] = Whh[(size_t)(j0 + ty + i) * 128 + k0 + tx];
    }
    __syncthreads();
#pragma unroll
    for (int i = 0; i < 32; i += 8) {
        float v = ta[tx][ty + i];
        if (hh) v += tb[tx][ty + i];
        Wcomb[(size_t)(k0 + ty + i) * 512 + j0 + tx] = v;
    }
}

// ---- FP32 GEMM: Y[M,128] = X[M,128] @ W[128,128], 64-row tile (round-6 version) ----
__global__ __launch_bounds__(256) void k_gemm(const float* __restrict__ X, const float* __restrict__ W,
                                              float* __restrict__ Y, int M) {
    __shared__ float Xs[32][68];
    __shared__ float Ws[32][128];
    int block_row = blockIdx.x * 64;
    int tid = threadIdx.x;
    int trr = tid >> 4;
    int tc = tid & 15;
    float acc[4][8] = {};
    for (int k0 = 0; k0 < 128; k0 += 32) {
        for (int i = tid; i < 512; i += 256) {
            int r = i >> 3, kk = (i & 7) << 2;
            int row = block_row + r;
            float4 v = make_float4(0.f, 0.f, 0.f, 0.f);
            if (row < M) v = *(const float4*)&X[(size_t)row * D + k0 + kk];
            Xs[kk + 0][r] = v.x; Xs[kk + 1][r] = v.y; Xs[kk + 2][r] = v.z; Xs[kk + 3][r] = v.w;
        }
        for (int i = tid; i < 1024; i += 256) {
            int r = i >> 5, cc = (i & 31) << 2;
            *(float4*)&Ws[r][cc] = *(const float4*)&W[(size_t)(k0 + r) * D + cc];
        }
        __syncthreads();
#pragma unroll
        for (int k = 0; k < 32; ++k) {
            float4 xv = *(const float4*)&Xs[k][trr * 4];
            float4 w0 = *(const float4*)&Ws[k][tc * 4];
            float4 w1 = *(const float4*)&Ws[k][tc * 4 + 64];
            float xr[4] = {xv.x, xv.y, xv.z, xv.w};
            float wc[8] = {w0.x, w0.y, w0.z, w0.w, w1.x, w1.y, w1.z, w1.w};
#pragma unroll
            for (int r = 0; r < 4; ++r)
#pragma unroll
                for (int c = 0; c < 8; ++c)
                    acc[r][c] += xr[r] * wc[c];
        }
        __syncthreads();
    }
    for (int r = 0; r < 4; ++r) {
        int row = block_row + trr * 4 + r;
        if (row < M) {
            *(float4*)&Y[(size_t)row * D + tc * 4] = make_float4(acc[r][0], acc[r][1], acc[r][2], acc[r][3]);
            *(float4*)&Y[(size_t)row * D + 64 + tc * 4] = make_float4(acc[r][4], acc[r][5], acc[r][6], acc[r][7]);
        }
    }
}

// ---- CSR gather aggregation, wave-per-node, 8 rows in flight ----
// norm factored: out[n] = dinv[n] * sum_e dinv[s]*xw[s] + xw[n]*dinv[n]^2 + b
template <bool RELU>
__global__ __launch_bounds__(256) void k_agg(const float* __restrict__ xw, const int* __restrict__ s_sorted,
                                             const int* __restrict__ row_ptr, const float* __restrict__ dinv,
                                             const float* __restrict__ bias, float* __restrict__ out, int N) {
    int n = blockIdx.x * 4 + (threadIdx.x >> 6);
    if (n >= N) return;
    int l = threadIdx.x & 63;
    int beg = row_ptr[n], end = row_ptr[n + 1];
    float2 a[8];
#pragma unroll
    for (int k = 0; k < 8; ++k) a[k] = make_float2(0.f, 0.f);
    for (int e = beg; e < end; e += 8) {
#pragma unroll
        for (int k = 0; k < 8; ++k) {
            int ee = min(e + k, end - 1);
            int s = s_sorted[ee];
            float ds = dinv[s];                 // L2-hot broadcast (200KB array)
            ds = (e + k < end) ? ds : 0.f;
            float2 xv = *(const float2*)&xw[(size_t)s * D + 2 * l];
            a[k].x += xv.x * ds;
            a[k].y += xv.y * ds;
        }
    }
    float din = dinv[n];
    float dw = din * din;
    float2 xs = *(const float2*)&xw[(size_t)n * D + 2 * l];
    float2 bv = *(const float2*)&bias[2 * l];
    float rx = (((a[0].x + a[1].x) + (a[2].x + a[3].x)) + ((a[4].x + a[5].x) + (a[6].x + a[7].x))) * din
               + xs.x * dw + bv.x;
    float ry = (((a[0].y + a[1].y) + (a[2].y + a[3].y)) + ((a[4].y + a[5].y) + (a[6].y + a[7].y))) * din
               + xs.y * dw + bv.y;
    if (RELU) { rx = fmaxf(rx, 0.f); ry = fmaxf(ry, 0.f); }
    *(float2*)&out[(size_t)n * D + 2 * l] = make_float2(rx, ry);
}

// ---- batched LSTM gates GEMM: gates[256][512] = q_star[256][256] @ Wcomb[256][512] ----
__global__ __launch_bounds__(256) void k_lstm_gemm(const float* __restrict__ q_star,
                                                   const float* __restrict__ Wcomb,
                                                   float* __restrict__ gates) {
    __shared__ float Xs[32][68];
    __shared__ float Ws[32][64];
    int tid = threadIdx.x;
    int bm = blockIdx.x & 3, bn = blockIdx.x >> 2;
    int m0 = bm * 64, n0 = bn * 64;
    int trr = tid >> 4;
    int tc = tid & 15;
    float acc[4][4] = {};
    for (int k0 = 0; k0 < 256; k0 += 32) {
        for (int i = tid; i < 512; i += 256) {
            int r = i >> 3, kk = (i & 7) << 2;
            float4 v = *(const float4*)&q_star[(size_t)(m0 + r) * 256 + k0 + kk];
            Xs[kk + 0][r] = v.x; Xs[kk + 1][r] = v.y; Xs[kk + 2][r] = v.z; Xs[kk + 3][r] = v.w;
        }
        for (int i = tid; i < 512; i += 256) {
            int r = i >> 4, c = (i & 15) << 2;
            *(float4*)&Ws[r][c] = *(const float4*)&Wcomb[(size_t)(k0 + r) * 512 + n0 + c];
        }
        __syncthreads();
#pragma unroll
        for (int k = 0; k < 32; ++k) {
            float4 xv = *(const float4*)&Xs[k][trr * 4];
            float4 wv = *(const float4*)&Ws[k][tc * 4];
            float xr[4] = {xv.x, xv.y, xv.z, xv.w};
            float wc[4] = {wv.x, wv.y, wv.z, wv.w};
#pragma unroll
            for (int r = 0; r < 4; ++r)
#pragma unroll
                for (int c = 0; c < 4; ++c)
                    acc[r][c] += xr[r] * wc[c];
        }
        __syncthreads();
    }
#pragma unroll
    for (int r = 0; r < 4; ++r)
        *(float4*)&gates[(size_t)(m0 + trr * 4 + r) * 512 + n0 + tc * 4] =
            make_float4(acc[r][0], acc[r][1], acc[r][2], acc[r][3]);
}

// ---- per-graph: LSTM nonlinearity prologue + SINGLE-PASS online-softmax attention ----
template <bool FIRST>
__global__ __launch_bounds__(512) void k_attn2(const float* __restrict__ h2, const int* __restrict__ gstart,
                                               const float* __restrict__ gates, const float* __restrict__ bih,
                                               const float* __restrict__ bhh, float* __restrict__ c_all,
                                               float* __restrict__ q_star) {
    int g = blockIdx.x;
    int t = threadIdx.x;
    int wid = t >> 6, l = t & 63;
    int s = gstart[g], epos = gstart[g + 1];
    __shared__ float hs[D];
    __shared__ float wmax[8], wsum[8];
    __shared__ float2 racc2[512];
    if (t < D) {
        float ig = bih[t] + bhh[t];
        float fg = bih[t + D] + bhh[t + D];
        float gg = bih[t + 2 * D] + bhh[t + 2 * D];
        float og = bih[t + 3 * D] + bhh[t + 3 * D];
        if (!FIRST) {
            const float* gr = &gates[(size_t)g * 512];
            ig += gr[t]; fg += gr[t + D]; gg += gr[t + 2 * D]; og += gr[t + 3 * D];
        }
        float cprev = FIRST ? 0.f : c_all[g * D + t];
        float cc = sigmoidf_(fg) * cprev + sigmoidf_(ig) * tanhf(gg);
        float hh = sigmoidf_(og) * tanhf(cc);
        c_all[g * D + t] = cc;
        hs[t] = hh;
        q_star[(size_t)g * 2 * D + t] = hh;
    }
    __syncthreads();
    float2 qv = *(const float2*)&hs[2 * l];
    float m = -1e30f;
    float ssum = 0.f;
    float2 a = {0.f, 0.f};
    for (int i = s + wid * 4; i < epos; i += 32) {
        int i0 = i, i1 = min(i + 1, epos - 1), i2 = min(i + 2, epos - 1), i3 = min(i + 3, epos - 1);
        bool v1 = (i + 1 < epos), v2 = (i + 2 < epos), v3 = (i + 3 < epos);
        float2 x0 = *(const float2*)&h2[(size_t)i0 * D + 2 * l];
        float2 x1 = *(const float2*)&h2[(size_t)i1 * D + 2 * l];
        float2 x2 = *(const float2*)&h2[(size_t)i2 * D + 2 * l];
        float2 x3 = *(const float2*)&h2[(size_t)i3 * D + 2 * l];
        float d0 = x0.x * qv.x + x0.y * qv.y;
        float d1 = x1.x * qv.x + x1.y * qv.y;
        float d2 = x2.x * qv.x + x2.y * qv.y;
        float d3 = x3.x * qv.x + x3.y * qv.y;
#pragma unroll
        for (int off = 32; off; off >>= 1) {
            d0 += __shfl_xor(d0, off);
            d1 += __shfl_xor(d1, off);
            d2 += __shfl_xor(d2, off);
            d3 += __shfl_xor(d3, off);
        }
        {
            if (d0 > m) { float sc = expf(m - d0); a.x *= sc; a.y *= sc; ssum *= sc; m = d0; }
            float p = expf(d0 - m);
            ssum += p; a.x += p * x0.x; a.y += p * x0.y;
        }
        if (v1) {
            if (d1 > m) { float sc = expf(m - d1); a.x *= sc; a.y *= sc; ssum *= sc; m = d1; }
            float p = expf(d1 - m);
            ssum += p; a.x += p * x1.x; a.y += p * x1.y;
        }
        if (v2) {
            if (d2 > m) { float sc = expf(m - d2); a.x *= sc; a.y *= sc; ssum *= sc; m = d2; }
            float p = expf(d2 - m);
            ssum += p; a.x += p * x2.x; a.y += p * x2.y;
        }
        if (v3) {
            if (d3 > m) { float sc = expf(m - d3); a.x *= sc; a.y *= sc; ssum *= sc; m = d3; }
            float p = expf(d3 - m);
            ssum += p; a.x += p * x3.x; a.y += p * x3.y;
        }
    }
    if (l == 0) wmax[wid] = m;
    __syncthreads();
    float M = wmax[0];
#pragma unroll
    for (int w = 1; w < 8; ++w) M = fmaxf(M, wmax[w]);
    float fac = expf(m - M);
    a.x *= fac; a.y *= fac;
    ssum *= fac;
    if (l == 0) wsum[wid] = ssum;
    racc2[t] = a;
    __syncthreads();
    if (t < 64) {
        float S = 0.f;
#pragma unroll
        for (int w = 0; w < 8; ++w) S += wsum[w];
        float2 r = make_float2(0.f, 0.f);
#pragma unroll
        for (int w = 0; w < 8; ++w) { r.x += racc2[t + 64 * w].x; r.y += racc2[t + 64 * w].y; }
        float inv = 1.0f / (S + 1e-16f);
        q_star[(size_t)g * 2 * D + D + 2 * t] = r.x * inv;
        q_star[(size_t)g * 2 * D + D + 2 * t + 1] = r.y * inv;
    }
}

extern "C" void kernel_launch(void* const* d_in, const int* in_sizes, int n_in,
                              void* d_out, int out_size, void* d_ws, size_t ws_size,
                              hipStream_t stream) {
    const float* x = (const float*)d_in[0];
    const int* ei = (const int*)d_in[1];
    const int* batch = (const int*)d_in[2];
    const float* W1 = (const float*)d_in[3];
    const float* b1 = (const float*)d_in[4];
    const float* W2 = (const float*)d_in[5];
    const float* b2 = (const float*)d_in[6];
    const float* Wih = (const float*)d_in[7];
    const float* Whh = (const float*)d_in[8];
    const float* bih = (const float*)d_in[9];
    const float* bhh = (const float*)d_in[10];

    int N = in_sizes[2];          // 50000
    int E = in_sizes[1] / 2;      // 625000
    int G = out_size / (2 * D);   // 256
    const int* src = ei;
    const int* dst = ei + E;
    float* xbuf = (float*)d_in[0];  // reuse x's buffer for h1/h2 (inputs restored before every call)
    float* q_star = (float*)d_out;

    float* wsf = (float*)d_ws;
    int* wsi = (int*)d_ws;
    size_t off = 0;
    float* dinv = wsf + off;    off += N;
    int* degcnt = wsi + off;    off += N;
    int* row_ptr = wsi + off;   off += N + 1;
    int* bsum = wsi + off;      off += 256;
    off = (off + 3) & ~(size_t)3;
    int* fillc = wsi + off;     off += N;
    int* s_sorted = wsi + off;  off += E;
    off = (off + 3) & ~(size_t)3;
    float* bufA = wsf + off;    off += (size_t)N * D;
    int* gstart = wsi + off;    off += G + 1;
    off = (off + 3) & ~(size_t)3;
    float* Wcomb = wsf + off;   off += 256 * 512;
    float* gates = wsf + off;   off += (size_t)G * 512;
    float* c_all = wsf + off;   off += (size_t)G * D;

    hipMemsetAsync(degcnt, 0, N * sizeof(int), stream);

    int eb = (E + 255) / 256;
    int nb = (N + 255) / 256;
    k_deg<<<eb, 256, 0, stream>>>(dst, degcnt, E);
    k_scan1<<<nb, 256, 0, stream>>>(degcnt, row_ptr, bsum, dinv, fillc, N);
    k_scan2<<<1, 256, 0, stream>>>(bsum, nb, batch, gstart, N, G);
    k_scan3<<<nb, 256, 0, stream>>>(row_ptr, bsum, N, E);
    k_fill<<<eb, 256, 0, stream>>>(src, dst, row_ptr, fillc, s_sorted, E);
    k_prepw<<<128, 256, 0, stream>>>(Wih, Whh, Wcomb);

    int gb = (N + 63) / 64;
    k_gemm<<<gb, 256, 0, stream>>>(x, W1, bufA, N);
    k_agg<true><<<(N + 3) / 4, 256, 0, stream>>>(bufA, s_sorted, row_ptr, dinv, b1, xbuf, N);
    k_gemm<<<gb, 256, 0, stream>>>(xbuf, W2, bufA, N);
    k_agg<false><<<(N + 3) / 4, 256, 0, stream>>>(bufA, s_sorted, row_ptr, dinv, b2, xbuf, N);

    // step 0: q_star = 0 -> gates are pure biases; no GEMM needed
    k_attn2<true><<<G, 512, 0, stream>>>(xbuf, gstart, gates, bih, bhh, c_all, q_star);
    for (int step = 1; step < 3; ++step) {
        k_lstm_gemm<<<32, 256, 0, stream>>>(q_star, Wcomb, gates);
        k_attn2<false><<<G, 512, 0, stream>>>(xbuf, gstart, gates, bih, bhh, c_all, q_star);
    }
}

// Round 10
// 350.682 us; speedup vs baseline: 1.2463x; 1.1665x over previous
//
#include <hip/hip_runtime.h>
#include <hip/hip_fp16.h>
#include <math.h>

#define D 128

__device__ __forceinline__ float sigmoidf_(float x) { return 1.0f / (1.0f + expf(-x)); }

// ---- degree histogram over dst ----
__global__ void k_deg(const int* __restrict__ dst, int* __restrict__ cnt, int E) {
    int i = blockIdx.x * blockDim.x + threadIdx.x;
    if (i < E) atomicAdd(&cnt[dst[i]], 1);
}

// ---- 2-level scan (+ dinv + fillc-zero fused into pass 1, gstart fused into pass 2) ----
__global__ __launch_bounds__(256) void k_scan1(const int* __restrict__ cnt, int* __restrict__ row_ptr,
                                               int* __restrict__ bsum, float* __restrict__ dinv,
                                               int* __restrict__ fillc, int N) {
    __shared__ int sh[256];
    int t = threadIdx.x;
    int i = blockIdx.x * 256 + t;
    int v = (i < N) ? cnt[i] : 0;
    if (i < N) {
        dinv[i] = rsqrtf((float)v + 1.0f);
        fillc[i] = 0;
    }
    sh[t] = v;
    __syncthreads();
    for (int off = 1; off < 256; off <<= 1) {
        int u = (t >= off) ? sh[t - off] : 0;
        __syncthreads();
        sh[t] += u;
        __syncthreads();
    }
    if (i < N) row_ptr[i] = sh[t] - v;
    if (t == 255) bsum[blockIdx.x] = sh[255];
}

__global__ __launch_bounds__(256) void k_scan2(int* __restrict__ bsum, int nb,
                                               const int* __restrict__ batch, int* __restrict__ gstart,
                                               int N, int G) {
    __shared__ int sh[256];
    int t = threadIdx.x;
    int v = (t < nb) ? bsum[t] : 0;
    sh[t] = v;
    __syncthreads();
    for (int off = 1; off < 256; off <<= 1) {
        int u = (t >= off) ? sh[t - off] : 0;
        __syncthreads();
        sh[t] += u;
        __syncthreads();
    }
    if (t < nb) bsum[t] = sh[t] - v;
    for (int g = t; g <= G; g += 256) {
        int lo = 0, hi = N;
        while (lo < hi) {
            int mid = (lo + hi) >> 1;
            if (batch[mid] < g) lo = mid + 1; else hi = mid;
        }
        gstart[g] = lo;
    }
}

__global__ __launch_bounds__(256) void k_scan3(int* __restrict__ row_ptr, const int* __restrict__ bsum,
                                               int N, int E) {
    int i = blockIdx.x * 256 + threadIdx.x;
    if (i < N) row_ptr[i] += bsum[blockIdx.x];
    if (i == 0) row_ptr[N] = E;
}

// ---- counting-sort fill: ONLY the source-index scatter ----
__global__ void k_fill(const int* __restrict__ src, const int* __restrict__ dst,
                       const int* __restrict__ row_ptr, int* __restrict__ fillc,
                       int* __restrict__ s_sorted, int E) {
    int i = blockIdx.x * blockDim.x + threadIdx.x;
    if (i >= E) return;
    int s = src[i], d = dst[i];
    int pos = row_ptr[d] + atomicAdd(&fillc[d], 1);
    s_sorted[pos] = s;
}

// ---- Wcomb[k][j] = Wih[j][k] + (k<128 ? Whh[j][k] : 0) ; [256][512] ----
__global__ __launch_bounds__(256) void k_prepw(const float* __restrict__ Wih, const float* __restrict__ Whh,
                                               float* __restrict__ Wcomb) {
    __shared__ float ta[32][33], tb[32][33];
    int t = threadIdx.x;
    int tx = t & 31, ty = t >> 5;
    int bk = blockIdx.x & 7, bj = blockIdx.x >> 3;
    int k0 = bk * 32, j0 = bj * 32;
    bool hh = (k0 < 128);
#pragma unroll
    for (int i = 0; i < 32; i += 8) ta[ty + i][tx] = Wih[(size_t)(j0 + ty + i) * 256 + k0 + tx];
    if (hh) {
#pragma unroll
        for (int i = 0; i < 32; i += 8) tb[ty + i][tx] = Whh[(size_t)(j0 + ty + i) * 128 + k0 + tx];
    }
    __syncthreads();
#pragma unroll
    for (int i = 0; i < 32; i += 8) {
        float v = ta[tx][ty + i];
        if (hh) v += tb[tx][ty + i];
        Wcomb[(size_t)(k0 + ty + i) * 512 + j0 + tx] = v;
    }
}

// ---- FP32 GEMM: Y16[M,128] = fp16(dinv[row] * (X[M,128] @ W[128,128])) ----
// 64-row tile; epilogue pre-scales by dinv and packs to half2 (halves gather bytes downstream)
__global__ __launch_bounds__(256) void k_gemm(const float* __restrict__ X, const float* __restrict__ W,
                                              const float* __restrict__ dinv, __half* __restrict__ Y, int M) {
    __shared__ float Xs[32][68];
    __shared__ float Ws[32][128];
    int block_row = blockIdx.x * 64;
    int tid = threadIdx.x;
    int trr = tid >> 4;
    int tc = tid & 15;
    float acc[4][8] = {};
    for (int k0 = 0; k0 < 128; k0 += 32) {
        for (int i = tid; i < 512; i += 256) {
            int r = i >> 3, kk = (i & 7) << 2;
            int row = block_row + r;
            float4 v = make_float4(0.f, 0.f, 0.f, 0.f);
            if (row < M) v = *(const float4*)&X[(size_t)row * D + k0 + kk];
            Xs[kk + 0][r] = v.x; Xs[kk + 1][r] = v.y; Xs[kk + 2][r] = v.z; Xs[kk + 3][r] = v.w;
        }
        for (int i = tid; i < 1024; i += 256) {
            int r = i >> 5, cc = (i & 31) << 2;
            *(float4*)&Ws[r][cc] = *(const float4*)&W[(size_t)(k0 + r) * D + cc];
        }
        __syncthreads();
#pragma unroll
        for (int k = 0; k < 32; ++k) {
            float4 xv = *(const float4*)&Xs[k][trr * 4];
            float4 w0 = *(const float4*)&Ws[k][tc * 4];
            float4 w1 = *(const float4*)&Ws[k][tc * 4 + 64];
            float xr[4] = {xv.x, xv.y, xv.z, xv.w};
            float wc[8] = {w0.x, w0.y, w0.z, w0.w, w1.x, w1.y, w1.z, w1.w};
#pragma unroll
            for (int r = 0; r < 4; ++r)
#pragma unroll
                for (int c = 0; c < 8; ++c)
                    acc[r][c] += xr[r] * wc[c];
        }
        __syncthreads();
    }
    for (int r = 0; r < 4; ++r) {
        int row = block_row + trr * 4 + r;
        if (row < M) {
            float s = dinv[row];
            __half2* y0 = (__half2*)&Y[(size_t)row * D + tc * 4];
            y0[0] = __floats2half2_rn(acc[r][0] * s, acc[r][1] * s);
            y0[1] = __floats2half2_rn(acc[r][2] * s, acc[r][3] * s);
            __half2* y1 = (__half2*)&Y[(size_t)row * D + 64 + tc * 4];
            y1[0] = __floats2half2_rn(acc[r][4] * s, acc[r][5] * s);
            y1[1] = __floats2half2_rn(acc[r][6] * s, acc[r][7] * s);
        }
    }
}

// ---- CSR gather aggregation over fp16 prescaled rows, wave-per-node, 8 rows in flight ----
// val16[s] = xw[s]*dinv[s] ; out[n] = dinv[n]*(sum_e val16[s] + val16[n]) + b
template <bool RELU>
__global__ __launch_bounds__(256) void k_agg(const __half* __restrict__ xw, const int* __restrict__ s_sorted,
                                             const int* __restrict__ row_ptr, const float* __restrict__ dinv,
                                             const float* __restrict__ bias, float* __restrict__ out, int N) {
    int n = blockIdx.x * 4 + (threadIdx.x >> 6);
    if (n >= N) return;
    int l = threadIdx.x & 63;
    int beg = row_ptr[n], end = row_ptr[n + 1];
    float2 a[8];
#pragma unroll
    for (int k = 0; k < 8; ++k) a[k] = make_float2(0.f, 0.f);
    for (int e = beg; e < end; e += 8) {
#pragma unroll
        for (int k = 0; k < 8; ++k) {
            int idx = e + k;
            int ee = min(idx, end - 1);
            int s = s_sorted[ee];
            __half2 hv = *(const __half2*)&xw[(size_t)s * D + 2 * l];
            float2 xv = __half22float2(hv);
            bool ok = (idx < end);
            a[k].x += ok ? xv.x : 0.f;
            a[k].y += ok ? xv.y : 0.f;
        }
    }
    float din = dinv[n];
    __half2 hself = *(const __half2*)&xw[(size_t)n * D + 2 * l];
    float2 xs = __half22float2(hself);
    float2 bv = *(const float2*)&bias[2 * l];
    float sx = ((a[0].x + a[1].x) + (a[2].x + a[3].x)) + ((a[4].x + a[5].x) + (a[6].x + a[7].x));
    float sy = ((a[0].y + a[1].y) + (a[2].y + a[3].y)) + ((a[4].y + a[5].y) + (a[6].y + a[7].y));
    float rx = (sx + xs.x) * din + bv.x;
    float ry = (sy + xs.y) * din + bv.y;
    if (RELU) { rx = fmaxf(rx, 0.f); ry = fmaxf(ry, 0.f); }
    *(float2*)&out[(size_t)n * D + 2 * l] = make_float2(rx, ry);
}

// ---- batched LSTM gates GEMM: gates[256][512] = q_star[256][256] @ Wcomb[256][512] ----
__global__ __launch_bounds__(256) void k_lstm_gemm(const float* __restrict__ q_star,
                                                   const float* __restrict__ Wcomb,
                                                   float* __restrict__ gates) {
    __shared__ float Xs[32][68];
    __shared__ float Ws[32][64];
    int tid = threadIdx.x;
    int bm = blockIdx.x & 3, bn = blockIdx.x >> 2;
    int m0 = bm * 64, n0 = bn * 64;
    int trr = tid >> 4;
    int tc = tid & 15;
    float acc[4][4] = {};
    for (int k0 = 0; k0 < 256; k0 += 32) {
        for (int i = tid; i < 512; i += 256) {
            int r = i >> 3, kk = (i & 7) << 2;
            float4 v = *(const float4*)&q_star[(size_t)(m0 + r) * 256 + k0 + kk];
            Xs[kk + 0][r] = v.x; Xs[kk + 1][r] = v.y; Xs[kk + 2][r] = v.z; Xs[kk + 3][r] = v.w;
        }
        for (int i = tid; i < 512; i += 256) {
            int r = i >> 4, c = (i & 15) << 2;
            *(float4*)&Ws[r][c] = *(const float4*)&Wcomb[(size_t)(k0 + r) * 512 + n0 + c];
        }
        __syncthreads();
#pragma unroll
        for (int k = 0; k < 32; ++k) {
            float4 xv = *(const float4*)&Xs[k][trr * 4];
            float4 wv = *(const float4*)&Ws[k][tc * 4];
            float xr[4] = {xv.x, xv.y, xv.z, xv.w};
            float wc[4] = {wv.x, wv.y, wv.z, wv.w};
#pragma unroll
            for (int r = 0; r < 4; ++r)
#pragma unroll
                for (int c = 0; c < 4; ++c)
                    acc[r][c] += xr[r] * wc[c];
        }
        __syncthreads();
    }
#pragma unroll
    for (int r = 0; r < 4; ++r)
        *(float4*)&gates[(size_t)(m0 + trr * 4 + r) * 512 + n0 + tc * 4] =
            make_float4(acc[r][0], acc[r][1], acc[r][2], acc[r][3]);
}

// ---- per-graph: LSTM nonlinearity prologue + SINGLE-PASS online-softmax attention ----
template <bool FIRST>
__global__ __launch_bounds__(512) void k_attn2(const float* __restrict__ h2, const int* __restrict__ gstart,
                                               const float* __restrict__ gates, const float* __restrict__ bih,
                                               const float* __restrict__ bhh, float* __restrict__ c_all,
                                               float* __restrict__ q_star) {
    int g = blockIdx.x;
    int t = threadIdx.x;
    int wid = t >> 6, l = t & 63;
    int s = gstart[g], epos = gstart[g + 1];
    __shared__ float hs[D];
    __shared__ float wmax[8], wsum[8];
    __shared__ float2 racc2[512];
    if (t < D) {
        float ig = bih[t] + bhh[t];
        float fg = bih[t + D] + bhh[t + D];
        float gg = bih[t + 2 * D] + bhh[t + 2 * D];
        float og = bih[t + 3 * D] + bhh[t + 3 * D];
        if (!FIRST) {
            const float* gr = &gates[(size_t)g * 512];
            ig += gr[t]; fg += gr[t + D]; gg += gr[t + 2 * D]; og += gr[t + 3 * D];
        }
        float cprev = FIRST ? 0.f : c_all[g * D + t];
        float cc = sigmoidf_(fg) * cprev + sigmoidf_(ig) * tanhf(gg);
        float hh = sigmoidf_(og) * tanhf(cc);
        c_all[g * D + t] = cc;
        hs[t] = hh;
        q_star[(size_t)g * 2 * D + t] = hh;
    }
    __syncthreads();
    float2 qv = *(const float2*)&hs[2 * l];
    float m = -1e30f;
    float ssum = 0.f;
    float2 a = {0.f, 0.f};
    for (int i = s + wid * 4; i < epos; i += 32) {
        int i0 = i, i1 = min(i + 1, epos - 1), i2 = min(i + 2, epos - 1), i3 = min(i + 3, epos - 1);
        bool v1 = (i + 1 < epos), v2 = (i + 2 < epos), v3 = (i + 3 < epos);
        float2 x0 = *(const float2*)&h2[(size_t)i0 * D + 2 * l];
        float2 x1 = *(const float2*)&h2[(size_t)i1 * D + 2 * l];
        float2 x2 = *(const float2*)&h2[(size_t)i2 * D + 2 * l];
        float2 x3 = *(const float2*)&h2[(size_t)i3 * D + 2 * l];
        float d0 = x0.x * qv.x + x0.y * qv.y;
        float d1 = x1.x * qv.x + x1.y * qv.y;
        float d2 = x2.x * qv.x + x2.y * qv.y;
        float d3 = x3.x * qv.x + x3.y * qv.y;
#pragma unroll
        for (int off = 32; off; off >>= 1) {
            d0 += __shfl_xor(d0, off);
            d1 += __shfl_xor(d1, off);
            d2 += __shfl_xor(d2, off);
            d3 += __shfl_xor(d3, off);
        }
        {
            if (d0 > m) { float sc = expf(m - d0); a.x *= sc; a.y *= sc; ssum *= sc; m = d0; }
            float p = expf(d0 - m);
            ssum += p; a.x += p * x0.x; a.y += p * x0.y;
        }
        if (v1) {
            if (d1 > m) { float sc = expf(m - d1); a.x *= sc; a.y *= sc; ssum *= sc; m = d1; }
            float p = expf(d1 - m);
            ssum += p; a.x += p * x1.x; a.y += p * x1.y;
        }
        if (v2) {
            if (d2 > m) { float sc = expf(m - d2); a.x *= sc; a.y *= sc; ssum *= sc; m = d2; }
            float p = expf(d2 - m);
            ssum += p; a.x += p * x2.x; a.y += p * x2.y;
        }
        if (v3) {
            if (d3 > m) { float sc = expf(m - d3); a.x *= sc; a.y *= sc; ssum *= sc; m = d3; }
            float p = expf(d3 - m);
            ssum += p; a.x += p * x3.x; a.y += p * x3.y;
        }
    }
    if (l == 0) wmax[wid] = m;
    __syncthreads();
    float M = wmax[0];
#pragma unroll
    for (int w = 1; w < 8; ++w) M = fmaxf(M, wmax[w]);
    float fac = expf(m - M);
    a.x *= fac; a.y *= fac;
    ssum *= fac;
    if (l == 0) wsum[wid] = ssum;
    racc2[t] = a;
    __syncthreads();
    if (t < 64) {
        float S = 0.f;
#pragma unroll
        for (int w = 0; w < 8; ++w) S += wsum[w];
        float2 r = make_float2(0.f, 0.f);
#pragma unroll
        for (int w = 0; w < 8; ++w) { r.x += racc2[t + 64 * w].x; r.y += racc2[t + 64 * w].y; }
        float inv = 1.0f / (S + 1e-16f);
        q_star[(size_t)g * 2 * D + D + 2 * t] = r.x * inv;
        q_star[(size_t)g * 2 * D + D + 2 * t + 1] = r.y * inv;
    }
}

extern "C" void kernel_launch(void* const* d_in, const int* in_sizes, int n_in,
                              void* d_out, int out_size, void* d_ws, size_t ws_size,
                              hipStream_t stream) {
    const float* x = (const float*)d_in[0];
    const int* ei = (const int*)d_in[1];
    const int* batch = (const int*)d_in[2];
    const float* W1 = (const float*)d_in[3];
    const float* b1 = (const float*)d_in[4];
    const float* W2 = (const float*)d_in[5];
    const float* b2 = (const float*)d_in[6];
    const float* Wih = (const float*)d_in[7];
    const float* Whh = (const float*)d_in[8];
    const float* bih = (const float*)d_in[9];
    const float* bhh = (const float*)d_in[10];

    int N = in_sizes[2];          // 50000
    int E = in_sizes[1] / 2;      // 625000
    int G = out_size / (2 * D);   // 256
    const int* src = ei;
    const int* dst = ei + E;
    float* xbuf = (float*)d_in[0];  // reuse x's buffer for h1/h2 (inputs restored before every call)
    float* q_star = (float*)d_out;

    float* wsf = (float*)d_ws;
    int* wsi = (int*)d_ws;
    size_t off = 0;
    float* dinv = wsf + off;    off += N;
    int* degcnt = wsi + off;    off += N;
    int* row_ptr = wsi + off;   off += N + 1;
    int* bsum = wsi + off;      off += 256;
    off = (off + 3) & ~(size_t)3;
    int* fillc = wsi + off;     off += N;
    int* s_sorted = wsi + off;  off += E;
    off = (off + 3) & ~(size_t)3;
    __half* bufA16 = (__half*)(wsf + off); off += (size_t)N * D / 2 + 4;  // fp16 prescaled xw
    int* gstart = wsi + off;    off += G + 1;
    off = (off + 3) & ~(size_t)3;
    float* Wcomb = wsf + off;   off += 256 * 512;
    float* gates = wsf + off;   off += (size_t)G * 512;
    float* c_all = wsf + off;   off += (size_t)G * D;

    hipMemsetAsync(degcnt, 0, N * sizeof(int), stream);

    int eb = (E + 255) / 256;
    int nb = (N + 255) / 256;
    k_deg<<<eb, 256, 0, stream>>>(dst, degcnt, E);
    k_scan1<<<nb, 256, 0, stream>>>(degcnt, row_ptr, bsum, dinv, fillc, N);
    k_scan2<<<1, 256, 0, stream>>>(bsum, nb, batch, gstart, N, G);
    k_scan3<<<nb, 256, 0, stream>>>(row_ptr, bsum, N, E);
    k_fill<<<eb, 256, 0, stream>>>(src, dst, row_ptr, fillc, s_sorted, E);
    k_prepw<<<128, 256, 0, stream>>>(Wih, Whh, Wcomb);

    int gb = (N + 63) / 64;
    k_gemm<<<gb, 256, 0, stream>>>(x, W1, dinv, bufA16, N);
    k_agg<true><<<(N + 3) / 4, 256, 0, stream>>>(bufA16, s_sorted, row_ptr, dinv, b1, xbuf, N);
    k_gemm<<<gb, 256, 0, stream>>>(xbuf, W2, dinv, bufA16, N);
    k_agg<false><<<(N + 3) / 4, 256, 0, stream>>>(bufA16, s_sorted, row_ptr, dinv, b2, xbuf, N);

    // step 0: q_star = 0 -> gates are pure biases; no GEMM needed
    k_attn2<true><<<G, 512, 0, stream>>>(xbuf, gstart, gates, bih, bhh, c_all, q_star);
    for (int step = 1; step < 3; ++step) {
        k_lstm_gemm<<<32, 256, 0, stream>>>(q_star, Wcomb, gates);
        k_attn2<false><<<G, 512, 0, stream>>>(xbuf, gstart, gates, bih, bhh, c_all, q_star);
    }
}

// Round 12
// 327.280 us; speedup vs baseline: 1.3354x; 1.0715x over previous
//
#include <hip/hip_runtime.h>
#include <hip/hip_fp16.h>
#include <math.h>

#define D 128

__device__ __forceinline__ float sigmoidf_(float x) { return 1.0f / (1.0f + expf(-x)); }

__device__ __forceinline__ float4 load4(const float* p) { return *(const float4*)p; }
__device__ __forceinline__ float4 load4(const __half* p) {
    __half2 h0 = *(const __half2*)p;
    __half2 h1 = *(const __half2*)(p + 2);
    float2 f0 = __half22float2(h0), f1 = __half22float2(h1);
    return make_float4(f0.x, f0.y, f1.x, f1.y);
}

// ---- degree histogram over dst; atomic return value = within-node rank ----
__global__ void k_deg(const int* __restrict__ dst, int* __restrict__ cnt, int* __restrict__ rank, int E) {
    int i = blockIdx.x * blockDim.x + threadIdx.x;
    if (i < E) rank[i] = atomicAdd(&cnt[dst[i]], 1);
}

// ---- 2-level scan (+ dinv fused into pass 1, gstart fused into pass 2) ----
__global__ __launch_bounds__(256) void k_scan1(const int* __restrict__ cnt, int* __restrict__ row_ptr,
                                               int* __restrict__ bsum, float* __restrict__ dinv, int N) {
    __shared__ int sh[256];
    int t = threadIdx.x;
    int i = blockIdx.x * 256 + t;
    int v = (i < N) ? cnt[i] : 0;
    if (i < N) dinv[i] = rsqrtf((float)v + 1.0f);
    sh[t] = v;
    __syncthreads();
    for (int off = 1; off < 256; off <<= 1) {
        int u = (t >= off) ? sh[t - off] : 0;
        __syncthreads();
        sh[t] += u;
        __syncthreads();
    }
    if (i < N) row_ptr[i] = sh[t] - v;
    if (t == 255) bsum[blockIdx.x] = sh[255];
}

__global__ __launch_bounds__(256) void k_scan2(int* __restrict__ bsum, int nb,
                                               const int* __restrict__ batch, int* __restrict__ gstart,
                                               int N, int G) {
    __shared__ int sh[256];
    int t = threadIdx.x;
    int v = (t < nb) ? bsum[t] : 0;
    sh[t] = v;
    __syncthreads();
    for (int off = 1; off < 256; off <<= 1) {
        int u = (t >= off) ? sh[t - off] : 0;
        __syncthreads();
        sh[t] += u;
        __syncthreads();
    }
    if (t < nb) bsum[t] = sh[t] - v;
    for (int g = t; g <= G; g += 256) {
        int lo = 0, hi = N;
        while (lo < hi) {
            int mid = (lo + hi) >> 1;
            if (batch[mid] < g) lo = mid + 1; else hi = mid;
        }
        gstart[g] = lo;
    }
}

__global__ __launch_bounds__(256) void k_scan3(int* __restrict__ row_ptr, const int* __restrict__ bsum,
                                               int N, int E) {
    int i = blockIdx.x * 256 + threadIdx.x;
    if (i < N) row_ptr[i] += bsum[blockIdx.x];
    if (i == 0) row_ptr[N] = E;
}

// ---- counting-sort fill via precomputed rank: no atomics, no fillc ----
__global__ void k_fill(const int* __restrict__ src, const int* __restrict__ dst,
                       const int* __restrict__ row_ptr, const int* __restrict__ rank,
                       int* __restrict__ s_sorted, int E) {
    int i = blockIdx.x * blockDim.x + threadIdx.x;
    if (i >= E) return;
    s_sorted[row_ptr[dst[i]] + rank[i]] = src[i];
}

// ---- Wcomb[k][j] = Wih[j][k] + (k<128 ? Whh[j][k] : 0) ; [256][512] ----
__global__ __launch_bounds__(256) void k_prepw(const float* __restrict__ Wih, const float* __restrict__ Whh,
                                               float* __restrict__ Wcomb) {
    __shared__ float ta[32][33], tb[32][33];
    int t = threadIdx.x;
    int tx = t & 31, ty = t >> 5;
    int bk = blockIdx.x & 7, bj = blockIdx.x >> 3;
    int k0 = bk * 32, j0 = bj * 32;
    bool hh = (k0 < 128);
#pragma unroll
    for (int i = 0; i < 32; i += 8) ta[ty + i][tx] = Wih[(size_t)(j0 + ty + i) * 256 + k0 + tx];
    if (hh) {
#pragma unroll
        for (int i = 0; i < 32; i += 8) tb[ty + i][tx] = Whh[(size_t)(j0 + ty + i) * 128 + k0 + tx];
    }
    __syncthreads();
#pragma unroll
    for (int i = 0; i < 32; i += 8) {
        float v = ta[tx][ty + i];
        if (hh) v += tb[tx][ty + i];
        Wcomb[(size_t)(k0 + ty + i) * 512 + j0 + tx] = v;
    }
}

// ---- GEMM: Y16[M,128] = fp16(dinv[row] * (X[M,128] @ W[128,128])), X fp32 or fp16 ----
template <typename T>
__global__ __launch_bounds__(256) void k_gemm(const T* __restrict__ X, const float* __restrict__ W,
                                              const float* __restrict__ dinv, __half* __restrict__ Y, int M) {
    __shared__ float Xs[32][68];
    __shared__ float Ws[32][128];
    int block_row = blockIdx.x * 64;
    int tid = threadIdx.x;
    int trr = tid >> 4;
    int tc = tid & 15;
    float acc[4][8] = {};
    for (int k0 = 0; k0 < 128; k0 += 32) {
        for (int i = tid; i < 512; i += 256) {
            int r = i >> 3, kk = (i & 7) << 2;
            int row = block_row + r;
            float4 v = make_float4(0.f, 0.f, 0.f, 0.f);
            if (row < M) v = load4(&X[(size_t)row * D + k0 + kk]);
            Xs[kk + 0][r] = v.x; Xs[kk + 1][r] = v.y; Xs[kk + 2][r] = v.z; Xs[kk + 3][r] = v.w;
        }
        for (int i = tid; i < 1024; i += 256) {
            int r = i >> 5, cc = (i & 31) << 2;
            *(float4*)&Ws[r][cc] = *(const float4*)&W[(size_t)(k0 + r) * D + cc];
        }
        __syncthreads();
#pragma unroll
        for (int k = 0; k < 32; ++k) {
            float4 xv = *(const float4*)&Xs[k][trr * 4];
            float4 w0 = *(const float4*)&Ws[k][tc * 4];
            float4 w1 = *(const float4*)&Ws[k][tc * 4 + 64];
            float xr[4] = {xv.x, xv.y, xv.z, xv.w};
            float wc[8] = {w0.x, w0.y, w0.z, w0.w, w1.x, w1.y, w1.z, w1.w};
#pragma unroll
            for (int r = 0; r < 4; ++r)
#pragma unroll
                for (int c = 0; c < 8; ++c)
                    acc[r][c] += xr[r] * wc[c];
        }
        __syncthreads();
    }
    for (int r = 0; r < 4; ++r) {
        int row = block_row + trr * 4 + r;
        if (row < M) {
            float s = dinv[row];
            __half2* y0 = (__half2*)&Y[(size_t)row * D + tc * 4];
            y0[0] = __floats2half2_rn(acc[r][0] * s, acc[r][1] * s);
            y0[1] = __floats2half2_rn(acc[r][2] * s, acc[r][3] * s);
            __half2* y1 = (__half2*)&Y[(size_t)row * D + 64 + tc * 4];
            y1[0] = __floats2half2_rn(acc[r][4] * s, acc[r][5] * s);
            y1[1] = __floats2half2_rn(acc[r][6] * s, acc[r][7] * s);
        }
    }
}

// ---- CSR gather aggregation over fp16 prescaled rows, fp16 output ----
// val16[s] = xw[s]*dinv[s] ; out[n] = fp16( dinv[n]*(sum_e val16[s] + val16[n]) + b )
template <bool RELU>
__global__ __launch_bounds__(256) void k_agg(const __half* __restrict__ xw, const int* __restrict__ s_sorted,
                                             const int* __restrict__ row_ptr, const float* __restrict__ dinv,
                                             const float* __restrict__ bias, __half* __restrict__ out, int N) {
    int n = blockIdx.x * 4 + (threadIdx.x >> 6);
    if (n >= N) return;
    int l = threadIdx.x & 63;
    int beg = row_ptr[n], end = row_ptr[n + 1];
    float2 a[8];
#pragma unroll
    for (int k = 0; k < 8; ++k) a[k] = make_float2(0.f, 0.f);
    for (int e = beg; e < end; e += 8) {
#pragma unroll
        for (int k = 0; k < 8; ++k) {
            int idx = e + k;
            int ee = min(idx, end - 1);
            int s = s_sorted[ee];
            __half2 hv = *(const __half2*)&xw[(size_t)s * D + 2 * l];
            float2 xv = __half22float2(hv);
            bool ok = (idx < end);
            a[k].x += ok ? xv.x : 0.f;
            a[k].y += ok ? xv.y : 0.f;
        }
    }
    float din = dinv[n];
    float2 xs = __half22float2(*(const __half2*)&xw[(size_t)n * D + 2 * l]);
    float2 bv = *(const float2*)&bias[2 * l];
    float sx = ((a[0].x + a[1].x) + (a[2].x + a[3].x)) + ((a[4].x + a[5].x) + (a[6].x + a[7].x));
    float sy = ((a[0].y + a[1].y) + (a[2].y + a[3].y)) + ((a[4].y + a[5].y) + (a[6].y + a[7].y));
    float rx = (sx + xs.x) * din + bv.x;
    float ry = (sy + xs.y) * din + bv.y;
    if (RELU) { rx = fmaxf(rx, 0.f); ry = fmaxf(ry, 0.f); }
    *(__half2*)&out[(size_t)n * D + 2 * l] = __floats2half2_rn(rx, ry);
}

// ---- batched LSTM gates GEMM: gates[256][512] = q_star[256][256] @ Wcomb[256][512] ----
__global__ __launch_bounds__(256) void k_lstm_gemm(const float* __restrict__ q_star,
                                                   const float* __restrict__ Wcomb,
                                                   float* __restrict__ gates) {
    __shared__ float Xs[32][68];
    __shared__ float Ws[32][64];
    int tid = threadIdx.x;
    int bm = blockIdx.x & 3, bn = blockIdx.x >> 2;
    int m0 = bm * 64, n0 = bn * 64;
    int trr = tid >> 4;
    int tc = tid & 15;
    float acc[4][4] = {};
    for (int k0 = 0; k0 < 256; k0 += 32) {
        for (int i = tid; i < 512; i += 256) {
            int r = i >> 3, kk = (i & 7) << 2;
            float4 v = *(const float4*)&q_star[(size_t)(m0 + r) * 256 + k0 + kk];
            Xs[kk + 0][r] = v.x; Xs[kk + 1][r] = v.y; Xs[kk + 2][r] = v.z; Xs[kk + 3][r] = v.w;
        }
        for (int i = tid; i < 512; i += 256) {
            int r = i >> 4, c = (i & 15) << 2;
            *(float4*)&Ws[r][c] = *(const float4*)&Wcomb[(size_t)(k0 + r) * 512 + n0 + c];
        }
        __syncthreads();
#pragma unroll
        for (int k = 0; k < 32; ++k) {
            float4 xv = *(const float4*)&Xs[k][trr * 4];
            float4 wv = *(const float4*)&Ws[k][tc * 4];
            float xr[4] = {xv.x, xv.y, xv.z, xv.w};
            float wc[4] = {wv.x, wv.y, wv.z, wv.w};
#pragma unroll
            for (int r = 0; r < 4; ++r)
#pragma unroll
                for (int c = 0; c < 4; ++c)
                    acc[r][c] += xr[r] * wc[c];
        }
        __syncthreads();
    }
#pragma unroll
    for (int r = 0; r < 4; ++r)
        *(float4*)&gates[(size_t)(m0 + trr * 4 + r) * 512 + n0 + tc * 4] =
            make_float4(acc[r][0], acc[r][1], acc[r][2], acc[r][3]);
}

// ---- per-graph: LSTM nonlinearity prologue + SINGLE-PASS online-softmax attention (fp16 h2) ----
template <bool FIRST>
__global__ __launch_bounds__(512) void k_attn2(const __half* __restrict__ h2, const int* __restrict__ gstart,
                                               const float* __restrict__ gates, const float* __restrict__ bih,
                                               const float* __restrict__ bhh, float* __restrict__ c_all,
                                               float* __restrict__ q_star) {
    int g = blockIdx.x;
    int t = threadIdx.x;
    int wid = t >> 6, l = t & 63;
    int s = gstart[g], epos = gstart[g + 1];
    __shared__ float hs[D];
    __shared__ float wmax[8], wsum[8];
    __shared__ float2 racc2[512];
    if (t < D) {
        float ig = bih[t] + bhh[t];
        float fg = bih[t + D] + bhh[t + D];
        float gg = bih[t + 2 * D] + bhh[t + 2 * D];
        float og = bih[t + 3 * D] + bhh[t + 3 * D];
        if (!FIRST) {
            const float* gr = &gates[(size_t)g * 512];
            ig += gr[t]; fg += gr[t + D]; gg += gr[t + 2 * D]; og += gr[t + 3 * D];
        }
        float cprev = FIRST ? 0.f : c_all[g * D + t];
        float cc = sigmoidf_(fg) * cprev + sigmoidf_(ig) * tanhf(gg);
        float hh = sigmoidf_(og) * tanhf(cc);
        c_all[g * D + t] = cc;
        hs[t] = hh;
        q_star[(size_t)g * 2 * D + t] = hh;
    }
    __syncthreads();
    float2 qv = *(const float2*)&hs[2 * l];
    float m = -1e30f;
    float ssum = 0.f;
    float2 a = {0.f, 0.f};
    for (int i = s + wid * 4; i < epos; i += 32) {
        int i0 = i, i1 = min(i + 1, epos - 1), i2 = min(i + 2, epos - 1), i3 = min(i + 3, epos - 1);
        bool v1 = (i + 1 < epos), v2 = (i + 2 < epos), v3 = (i + 3 < epos);
        float2 x0 = __half22float2(*(const __half2*)&h2[(size_t)i0 * D + 2 * l]);
        float2 x1 = __half22float2(*(const __half2*)&h2[(size_t)i1 * D + 2 * l]);
        float2 x2 = __half22float2(*(const __half2*)&h2[(size_t)i2 * D + 2 * l]);
        float2 x3 = __half22float2(*(const __half2*)&h2[(size_t)i3 * D + 2 * l]);
        float d0 = x0.x * qv.x + x0.y * qv.y;
        float d1 = x1.x * qv.x + x1.y * qv.y;
        float d2 = x2.x * qv.x + x2.y * qv.y;
        float d3 = x3.x * qv.x + x3.y * qv.y;
#pragma unroll
        for (int off = 32; off; off >>= 1) {
            d0 += __shfl_xor(d0, off);
            d1 += __shfl_xor(d1, off);
            d2 += __shfl_xor(d2, off);
            d3 += __shfl_xor(d3, off);
        }
        {
            if (d0 > m) { float sc = expf(m - d0); a.x *= sc; a.y *= sc; ssum *= sc; m = d0; }
            float p = expf(d0 - m);
            ssum += p; a.x += p * x0.x; a.y += p * x0.y;
        }
        if (v1) {
            if (d1 > m) { float sc = expf(m - d1); a.x *= sc; a.y *= sc; ssum *= sc; m = d1; }
            float p = expf(d1 - m);
            ssum += p; a.x += p * x1.x; a.y += p * x1.y;
        }
        if (v2) {
            if (d2 > m) { float sc = expf(m - d2); a.x *= sc; a.y *= sc; ssum *= sc; m = d2; }
            float p = expf(d2 - m);
            ssum += p; a.x += p * x2.x; a.y += p * x2.y;
        }
        if (v3) {
            if (d3 > m) { float sc = expf(m - d3); a.x *= sc; a.y *= sc; ssum *= sc; m = d3; }
            float p = expf(d3 - m);
            ssum += p; a.x += p * x3.x; a.y += p * x3.y;
        }
    }
    if (l == 0) wmax[wid] = m;
    __syncthreads();
    float M = wmax[0];
#pragma unroll
    for (int w = 1; w < 8; ++w) M = fmaxf(M, wmax[w]);
    float fac = expf(m - M);
    a.x *= fac; a.y *= fac;
    ssum *= fac;
    if (l == 0) wsum[wid] = ssum;
    racc2[t] = a;
    __syncthreads();
    if (t < 64) {
        float S = 0.f;
#pragma unroll
        for (int w = 0; w < 8; ++w) S += wsum[w];
        float2 r = make_float2(0.f, 0.f);
#pragma unroll
        for (int w = 0; w < 8; ++w) { r.x += racc2[t + 64 * w].x; r.y += racc2[t + 64 * w].y; }
        float inv = 1.0f / (S + 1e-16f);
        q_star[(size_t)g * 2 * D + D + 2 * t] = r.x * inv;
        q_star[(size_t)g * 2 * D + D + 2 * t + 1] = r.y * inv;
    }
}

extern "C" void kernel_launch(void* const* d_in, const int* in_sizes, int n_in,
                              void* d_out, int out_size, void* d_ws, size_t ws_size,
                              hipStream_t stream) {
    const float* x = (const float*)d_in[0];
    const int* ei = (const int*)d_in[1];
    const int* batch = (const int*)d_in[2];
    const float* W1 = (const float*)d_in[3];
    const float* b1 = (const float*)d_in[4];
    const float* W2 = (const float*)d_in[5];
    const float* b2 = (const float*)d_in[6];
    const float* Wih = (const float*)d_in[7];
    const float* Whh = (const float*)d_in[8];
    const float* bih = (const float*)d_in[9];
    const float* bhh = (const float*)d_in[10];

    int N = in_sizes[2];          // 50000
    int E = in_sizes[1] / 2;      // 625000
    int G = out_size / (2 * D);   // 256
    const int* src = ei;
    const int* dst = ei + E;
    float* q_star = (float*)d_out;

    float* wsf = (float*)d_ws;
    int* wsi = (int*)d_ws;
    size_t off = 0;
    float* dinv = wsf + off;    off += N;
    int* degcnt = wsi + off;    off += N;
    int* row_ptr = wsi + off;   off += N + 1;
    int* bsum = wsi + off;      off += 256;
    off = (off + 3) & ~(size_t)3;
    int* rank = wsi + off;      off += E;
    int* s_sorted = wsi + off;  off += E;
    off = (off + 3) & ~(size_t)3;
    __half* bufA16 = (__half*)(wsf + off); off += (size_t)N * D / 2 + 4;  // fp16 prescaled xw
    __half* h16 = (__half*)(wsf + off);    off += (size_t)N * D / 2 + 4;  // fp16 h1 / h2
    int* gstart = wsi + off;    off += G + 1;
    off = (off + 3) & ~(size_t)3;
    float* Wcomb = wsf + off;   off += 256 * 512;
    float* gates = wsf + off;   off += (size_t)G * 512;
    float* c_all = wsf + off;   off += (size_t)G * D;

    hipMemsetAsync(degcnt, 0, N * sizeof(int), stream);

    int eb = (E + 255) / 256;
    int nb = (N + 255) / 256;
    k_deg<<<eb, 256, 0, stream>>>(dst, degcnt, rank, E);
    k_scan1<<<nb, 256, 0, stream>>>(degcnt, row_ptr, bsum, dinv, N);
    k_scan2<<<1, 256, 0, stream>>>(bsum, nb, batch, gstart, N, G);
    k_scan3<<<nb, 256, 0, stream>>>(row_ptr, bsum, N, E);
    k_fill<<<eb, 256, 0, stream>>>(src, dst, row_ptr, rank, s_sorted, E);
    k_prepw<<<128, 256, 0, stream>>>(Wih, Whh, Wcomb);

    int gb = (N + 63) / 64;
    k_gemm<float><<<gb, 256, 0, stream>>>(x, W1, dinv, bufA16, N);
    k_agg<true><<<(N + 3) / 4, 256, 0, stream>>>(bufA16, s_sorted, row_ptr, dinv, b1, h16, N);
    k_gemm<__half><<<gb, 256, 0, stream>>>(h16, W2, dinv, bufA16, N);
    k_agg<false><<<(N + 3) / 4, 256, 0, stream>>>(bufA16, s_sorted, row_ptr, dinv, b2, h16, N);

    // step 0: q_star = 0 -> gates are pure biases; no GEMM needed
    k_attn2<true><<<G, 512, 0, stream>>>(h16, gstart, gates, bih, bhh, c_all, q_star);
    for (int step = 1; step < 3; ++step) {
        k_lstm_gemm<<<32, 256, 0, stream>>>(q_star, Wcomb, gates);
        k_attn2<false><<<G, 512, 0, stream>>>(h16, gstart, gates, bih, bhh, c_all, q_star);
    }
}